// Round 4
// baseline (503.083 us; speedup 1.0000x reference)
//
#include <hip/hip_runtime.h>
#include <hip/hip_bf16.h>

// x: [2, 2048, 1024] f32; mask: [2, 2048, 2048] f32; W_qkv: [1024, 3072] f32
// W_out: [1024, 1024] f32; b_out: [1024] f32; out: [2, 2048, 1024] f32
#define BATCH 2
#define SEQ   2048
#define DIM   1024
#define HEADS 16
#define DH    64
#define N_QKV 3072
#define M_TOT 4096
#define SCALE 0.125f
#define EPS   1e-10f

typedef __attribute__((ext_vector_type(8))) short short8;
typedef __attribute__((ext_vector_type(4))) float f32x4;

static __device__ __forceinline__ unsigned short f2bf(float f) {
    __hip_bfloat16 h = __float2bfloat16(f);
    return *reinterpret_cast<unsigned short*>(&h);
}
static __device__ __forceinline__ float bf2f(unsigned short u) {
    unsigned int x = ((unsigned int)u) << 16;
    return __builtin_bit_cast(float, x);
}
static __device__ __forceinline__ void glds16(const void* g, void* l) {
    __builtin_amdgcn_global_load_lds((const __attribute__((address_space(1))) void*)g,
                                     (__attribute__((address_space(3))) void*)l,
                                     16, 0, 0);
}

// ---------------------------------------------------------------------------
// Pre-pass: split fp32 -> bf16 hi + bf16 lo (residual).
// ---------------------------------------------------------------------------
__global__ __launch_bounds__(256) void convert_hilo(const float* __restrict__ s,
                                                    unsigned short* __restrict__ h,
                                                    unsigned short* __restrict__ l) {
    const int i = blockIdx.x * 256 + threadIdx.x;
    float4 v = reinterpret_cast<const float4*>(s)[i];
    ushort4 hv, lv;
    hv.x = f2bf(v.x); lv.x = f2bf(v.x - bf2f(hv.x));
    hv.y = f2bf(v.y); lv.y = f2bf(v.y - bf2f(hv.y));
    hv.z = f2bf(v.z); lv.z = f2bf(v.z - bf2f(hv.z));
    hv.w = f2bf(v.w); lv.w = f2bf(v.w - bf2f(hv.w));
    reinterpret_cast<ushort4*>(h)[i] = hv;
    reinterpret_cast<ushort4*>(l)[i] = lv;
}

// ---------------------------------------------------------------------------
// Pre-pass: W [rows(k)][cols(n)] fp32 -> WT hi/lo bf16 [n][k]
// ---------------------------------------------------------------------------
__global__ __launch_bounds__(256) void transpose_hilo(const float* __restrict__ src,
                                                      unsigned short* __restrict__ th,
                                                      unsigned short* __restrict__ tl,
                                                      int rows, int cols) {
    __shared__ float tile[32][33];
    const int c0 = blockIdx.x * 32, r0 = blockIdx.y * 32;
    const int tx = threadIdx.x & 31, ty = threadIdx.x >> 5;
    #pragma unroll
    for (int i = ty; i < 32; i += 8)
        tile[i][tx] = src[(long)(r0 + i) * cols + c0 + tx];
    __syncthreads();
    #pragma unroll
    for (int i = ty; i < 32; i += 8) {
        float v = tile[tx][i];
        unsigned short hv = f2bf(v);
        th[(long)(c0 + i) * rows + r0 + tx] = hv;
        tl[(long)(c0 + i) * rows + r0 + tx] = f2bf(v - bf2f(hv));
    }
}

// ---------------------------------------------------------------------------
// bf16x3 MFMA GEMM (round-3 verified): C ~= AhBh + AhBl + AlBh, fp32 acc.
// ---------------------------------------------------------------------------
template <int EPI>
__global__ __launch_bounds__(256) void gemm_bf16x3(
    const unsigned short* __restrict__ Ahg, const unsigned short* __restrict__ Alg,
    const unsigned short* __restrict__ Bhg, const unsigned short* __restrict__ Blg,
    unsigned short* __restrict__ qb, unsigned short* __restrict__ kb,
    unsigned short* __restrict__ vtb,
    const float* __restrict__ bias, float* __restrict__ out) {
    __shared__ __align__(16) unsigned short Ah_s[128 * 32];
    __shared__ __align__(16) unsigned short Al_s[128 * 32];
    __shared__ __align__(16) unsigned short Bh_s[128 * 32];
    __shared__ __align__(16) unsigned short Bl_s[128 * 32];

    const int n0   = blockIdx.x * 128;
    const int m0   = blockIdx.y * 128;
    const int wave = threadIdx.x >> 6;
    const int lane = threadIdx.x & 63;
    const int l16  = lane & 15;
    const int g    = lane >> 4;
    const int wm   = wave & 1;
    const int wn   = wave >> 1;

    const int srow   = lane >> 2;
    const int schunk = (lane & 3) * 8;

    f32x4 acc[4][4] = {};

    for (int k0 = 0; k0 < DIM; k0 += 32) {
        #pragma unroll
        for (int i = 0; i < 2; ++i) {
            const int row = wave * 32 + i * 16;
            const long ga = (long)(m0 + row + srow) * DIM + k0 + schunk;
            const long gb = (long)(n0 + row + srow) * DIM + k0 + schunk;
            glds16(Ahg + ga, &Ah_s[row * 32]);
            glds16(Alg + ga, &Al_s[row * 32]);
            glds16(Bhg + gb, &Bh_s[row * 32]);
            glds16(Blg + gb, &Bl_s[row * 32]);
        }
        __syncthreads();

        short8 ah[4], al[4];
        #pragma unroll
        for (int mt = 0; mt < 4; ++mt) {
            const int r = (wm * 64 + mt * 16 + l16) * 32 + g * 8;
            ah[mt] = *reinterpret_cast<const short8*>(&Ah_s[r]);
            al[mt] = *reinterpret_cast<const short8*>(&Al_s[r]);
        }
        #pragma unroll
        for (int nt = 0; nt < 4; ++nt) {
            const int r = (wn * 64 + nt * 16 + l16) * 32 + g * 8;
            const short8 bh = *reinterpret_cast<const short8*>(&Bh_s[r]);
            const short8 bl = *reinterpret_cast<const short8*>(&Bl_s[r]);
            #pragma unroll
            for (int mt = 0; mt < 4; ++mt) {
                acc[mt][nt] = __builtin_amdgcn_mfma_f32_16x16x32_bf16(ah[mt], bh, acc[mt][nt], 0, 0, 0);
                acc[mt][nt] = __builtin_amdgcn_mfma_f32_16x16x32_bf16(ah[mt], bl, acc[mt][nt], 0, 0, 0);
                acc[mt][nt] = __builtin_amdgcn_mfma_f32_16x16x32_bf16(al[mt], bh, acc[mt][nt], 0, 0, 0);
            }
        }
        __syncthreads();
    }

    if constexpr (EPI == 0) {
        #pragma unroll
        for (int nt = 0; nt < 4; ++nt) {
            const int n     = n0 + wn * 64 + nt * 16 + l16;
            const int which = n >> 10;
            const int rem   = n & 1023;
            const int head  = rem >> 6;
            const int d     = rem & 63;
            #pragma unroll
            for (int mt = 0; mt < 4; ++mt) {
                #pragma unroll
                for (int r = 0; r < 4; ++r) {
                    const int m  = m0 + wm * 64 + mt * 16 + g * 4 + r;
                    const int bb = m >> 11;
                    const int li = m & 2047;
                    const int bh_i = bb * HEADS + head;
                    const float val = acc[mt][nt][r];
                    if (which == 0)
                        qb[((long)bh_i * SEQ + li) * DH + d] = f2bf(val * SCALE);
                    else if (which == 1)
                        kb[((long)bh_i * SEQ + li) * DH + d] = f2bf(val);
                    else
                        vtb[((long)bh_i * DH + d) * SEQ + li] = f2bf(val);
                }
            }
        }
    } else {
        #pragma unroll
        for (int nt = 0; nt < 4; ++nt) {
            const int n  = n0 + wn * 64 + nt * 16 + l16;
            const float bv = bias[n];
            #pragma unroll
            for (int mt = 0; mt < 4; ++mt) {
                #pragma unroll
                for (int r = 0; r < 4; ++r) {
                    const int m = m0 + wm * 64 + mt * 16 + g * 4 + r;
                    out[(long)m * DIM + n] = acc[mt][nt][r] + bv;
                }
            }
        }
    }
}

// ---------------------------------------------------------------------------
// MFMA flash attention, j-split x4: block = 16 q rows, wave w covers
// j in [w*512, w*512+512). No per-iter barriers (wave-private LDS).
// Wave-uniform lazy max; Z dropped (eps*Z -> 2048*eps, |delta| < 1e-6).
// End: LDS combine of 4 partials, emit z as bf16 hi/lo.
// ---------------------------------------------------------------------------
__global__ __launch_bounds__(256) void attn_mfma(const unsigned short* __restrict__ qb,
                                                 const unsigned short* __restrict__ kb,
                                                 const unsigned short* __restrict__ vtb,
                                                 const float* __restrict__ mask,
                                                 unsigned short* __restrict__ zh,
                                                 unsigned short* __restrict__ zl) {
    const int qt   = blockIdx.x;            // 0..127 (16-row tiles)
    const int h    = blockIdx.y;
    const int bb   = blockIdx.z;
    const int bh   = bb * HEADS + h;
    const int wave = threadIdx.x >> 6;
    const int lane = threadIdx.x & 63;
    const int l16  = lane & 15;
    const int g    = lane >> 4;

    const int i0    = qt * 16;              // q rows shared by all 4 waves
    const int jbase = wave * 512;           // this wave's j-range

    __shared__ struct {
        union {
            unsigned short p[4][16][72];    // P staging (wave-private)
            float cmb[4][16][65];           // combine buffer (padded: stride 65)
        } u;
        float statM[4];
        float statZ[4][16];
    } sm;

    const unsigned short* qptr = qb + ((long)bh * SEQ + i0 + l16) * DH + g * 8;
    const short8 q0 = *reinterpret_cast<const short8*>(qptr);
    const short8 q1 = *reinterpret_cast<const short8*>(qptr + 32);

    f32x4 o[4] = {};
    float Zpm[4] = {0.f, 0.f, 0.f, 0.f};
    float m_w = -INFINITY;                  // wave-uniform running max

    const float* maskb = mask + (long)bb * SEQ * SEQ;

    for (int it = 0; it < 8; ++it) {
        const int j0 = jbase + it * 64;

        // ---- S = Q K^T ----
        f32x4 s[4];
        #pragma unroll
        for (int nt = 0; nt < 4; ++nt) {
            const unsigned short* kp = kb + ((long)bh * SEQ + j0 + nt * 16 + l16) * DH + g * 8;
            short8 k0 = *reinterpret_cast<const short8*>(kp);
            short8 k1 = *reinterpret_cast<const short8*>(kp + 32);
            f32x4 acc = {0.f, 0.f, 0.f, 0.f};
            acc = __builtin_amdgcn_mfma_f32_16x16x32_bf16(q0, k0, acc, 0, 0, 0);
            acc = __builtin_amdgcn_mfma_f32_16x16x32_bf16(q1, k1, acc, 0, 0, 0);
            s[nt] = acc;
        }

        // ---- wave-uniform tile max (all 64 lanes -> one value) ----
        float tmax = fmaxf(fmaxf(fmaxf(s[0][0], s[0][1]), fmaxf(s[0][2], s[0][3])),
                           fmaxf(fmaxf(s[1][0], s[1][1]), fmaxf(s[1][2], s[1][3])));
        tmax = fmaxf(tmax, fmaxf(fmaxf(fmaxf(s[2][0], s[2][1]), fmaxf(s[2][2], s[2][3])),
                                 fmaxf(fmaxf(s[3][0], s[3][1]), fmaxf(s[3][2], s[3][3]))));
        #pragma unroll
        for (int off = 1; off < 64; off <<= 1)
            tmax = fmaxf(tmax, __shfl_xor(tmax, off, 64));
        const float tmax_u = __builtin_bit_cast(float,
            __builtin_amdgcn_readfirstlane(__builtin_bit_cast(int, tmax)));

        // ---- lazy rescale (wave-uniform branch; taken rarely after warmup) ----
        if (tmax_u > m_w) {
            const float alpha = __expf(m_w - tmax_u);   // iter 0: exp(-inf)=0
            m_w = tmax_u;
            #pragma unroll
            for (int r = 0; r < 4; ++r) Zpm[r] *= alpha;
            #pragma unroll
            for (int nt = 0; nt < 4; ++nt)
                #pragma unroll
                for (int r = 0; r < 4; ++r) o[nt][r] *= alpha;
        }

        // ---- p = exp(s - m), mask, stage bf16 P ----
        #pragma unroll
        for (int nt = 0; nt < 4; ++nt) {
            #pragma unroll
            for (int r = 0; r < 4; ++r) {
                const int row = g * 4 + r;
                const int col = nt * 16 + l16;
                float p  = __expf(s[nt][r] - m_w);
                float mv = maskb[(long)(i0 + row) * SEQ + j0 + col];
                float pm = p * mv;
                Zpm[r]  += pm;
                sm.u.p[wave][row][col] = f2bf(pm);
            }
        }

        // ---- O += P V (wave-private LDS round-trip; no barrier needed) ----
        #pragma unroll
        for (int jc = 0; jc < 2; ++jc) {
            const short8 pf = *reinterpret_cast<const short8*>(&sm.u.p[wave][l16][jc * 32 + g * 8]);
            #pragma unroll
            for (int nt = 0; nt < 4; ++nt) {
                const unsigned short* vp =
                    vtb + ((long)bh * DH + nt * 16 + l16) * SEQ + j0 + jc * 32 + g * 8;
                short8 vf = *reinterpret_cast<const short8*>(vp);
                o[nt] = __builtin_amdgcn_mfma_f32_16x16x32_bf16(pf, vf, o[nt], 0, 0, 0);
            }
        }
    }

    // ---- reduce Zpm across the 16-lane groups ----
    #pragma unroll
    for (int off = 1; off < 16; off <<= 1)
        #pragma unroll
        for (int r = 0; r < 4; ++r)
            Zpm[r] += __shfl_xor(Zpm[r], off, 64);

    __syncthreads();   // all waves done with u.p before it's reused as cmb

    // ---- write partials ----
    #pragma unroll
    for (int nt = 0; nt < 4; ++nt)
        #pragma unroll
        for (int r = 0; r < 4; ++r)
            sm.u.cmb[wave][g * 4 + r][nt * 16 + l16] = o[nt][r];
    if (lane == 0) sm.statM[wave] = m_w;
    if (l16 == 0) {
        #pragma unroll
        for (int r = 0; r < 4; ++r) sm.statZ[wave][g * 4 + r] = Zpm[r];
    }
    __syncthreads();

    // ---- combine 4 j-partials, normalize, store bf16 hi/lo ----
    const int col = threadIdx.x & 63;
    const int rw  = threadIdx.x >> 6;
    const float M = fmaxf(fmaxf(sm.statM[0], sm.statM[1]),
                          fmaxf(sm.statM[2], sm.statM[3]));
    float sc[4];
    #pragma unroll
    for (int w = 0; w < 4; ++w) sc[w] = __expf(sm.statM[w] - M);

    #pragma unroll
    for (int e = 0; e < 4; ++e) {
        const int row = rw * 4 + e;
        float ov = 0.f, Zt = 0.f;
        #pragma unroll
        for (int w = 0; w < 4; ++w) {
            ov += sc[w] * sm.u.cmb[w][row][col];
            Zt += sc[w] * sm.statZ[w][row];
        }
        const float val = ov / (Zt + 2048.0f * EPS);
        const long idx = ((long)bb * SEQ + i0 + row) * DIM + h * DH + col;
        const unsigned short hv = f2bf(val);
        zh[idx] = hv;
        zl[idx] = f2bf(val - bf2f(hv));
    }
}

// ---------------------------------------------------------------------------
extern "C" void kernel_launch(void* const* d_in, const int* in_sizes, int n_in,
                              void* d_out, int out_size, void* d_ws, size_t ws_size,
                              hipStream_t stream) {
    const float* x     = (const float*)d_in[0];
    const float* mask  = (const float*)d_in[1];
    const float* W_qkv = (const float*)d_in[2];
    const float* W_out = (const float*)d_in[3];
    const float* b_out = (const float*)d_in[4];
    float* out = (float*)d_out;

    unsigned short* ws = (unsigned short*)d_ws;
    unsigned short* xh   = ws;                 // 4M  (reused as zh after gemm1)
    unsigned short* xl   = xh   + 4194304;     // 4M  (reused as zl)
    unsigned short* WqTh = xl   + 4194304;     // 3M
    unsigned short* WqTl = WqTh + 3145728;     // 3M
    unsigned short* WoTh = WqTl + 3145728;     // 1M
    unsigned short* WoTl = WoTh + 1048576;     // 1M
    unsigned short* qb   = WoTl + 1048576;     // 4M
    unsigned short* kb   = qb   + 4194304;     // 4M
    unsigned short* vtb  = kb   + 4194304;     // 4M  -> total 56 MB
    unsigned short* zzh  = xh;
    unsigned short* zzl  = xl;

    convert_hilo<<<4096, 256, 0, stream>>>(x, xh, xl);
    transpose_hilo<<<dim3(96, 32), 256, 0, stream>>>(W_qkv, WqTh, WqTl, 1024, 3072);
    transpose_hilo<<<dim3(32, 32), 256, 0, stream>>>(W_out, WoTh, WoTl, 1024, 1024);

    gemm_bf16x3<0><<<dim3(24, 32), 256, 0, stream>>>(xh, xl, WqTh, WqTl,
                                                     qb, kb, vtb, nullptr, nullptr);

    attn_mfma<<<dim3(SEQ / 16, HEADS, BATCH), 256, 0, stream>>>(qb, kb, vtb, mask, zzh, zzl);

    gemm_bf16x3<1><<<dim3(8, 32), 256, 0, stream>>>(zzh, zzl, WoTh, WoTl,
                                                    nullptr, nullptr, nullptr, b_out, out);
}

// Round 5
// 357.645 us; speedup vs baseline: 1.4067x; 1.4067x over previous
//
#include <hip/hip_runtime.h>
#include <hip/hip_bf16.h>

// x: [2, 2048, 1024] f32; mask: [2, 2048, 2048] f32; W_qkv: [1024, 3072] f32
// W_out: [1024, 1024] f32; b_out: [1024] f32; out: [2, 2048, 1024] f32
#define BATCH 2
#define SEQ   2048
#define DIM   1024
#define HEADS 16
#define DH    64
#define N_QKV 3072
#define M_TOT 4096
#define SCALE 0.125f
#define EPS   1e-10f

typedef __attribute__((ext_vector_type(8))) short short8;
typedef __attribute__((ext_vector_type(4))) float f32x4;

static __device__ __forceinline__ unsigned short f2bf(float f) {
    __hip_bfloat16 h = __float2bfloat16(f);
    return *reinterpret_cast<unsigned short*>(&h);
}
static __device__ __forceinline__ float bf2f(unsigned short u) {
    unsigned int x = ((unsigned int)u) << 16;
    return __builtin_bit_cast(float, x);
}
static __device__ __forceinline__ void glds16(const void* g, void* l) {
    __builtin_amdgcn_global_load_lds((const __attribute__((address_space(1))) void*)g,
                                     (__attribute__((address_space(3))) void*)l,
                                     16, 0, 0);
}

// ---------------------------------------------------------------------------
// Pre-pass: split fp32 -> bf16 hi + bf16 lo (residual).
// ---------------------------------------------------------------------------
__global__ __launch_bounds__(256) void convert_hilo(const float* __restrict__ s,
                                                    unsigned short* __restrict__ h,
                                                    unsigned short* __restrict__ l) {
    const int i = blockIdx.x * 256 + threadIdx.x;
    float4 v = reinterpret_cast<const float4*>(s)[i];
    ushort4 hv, lv;
    hv.x = f2bf(v.x); lv.x = f2bf(v.x - bf2f(hv.x));
    hv.y = f2bf(v.y); lv.y = f2bf(v.y - bf2f(hv.y));
    hv.z = f2bf(v.z); lv.z = f2bf(v.z - bf2f(hv.z));
    hv.w = f2bf(v.w); lv.w = f2bf(v.w - bf2f(hv.w));
    reinterpret_cast<ushort4*>(h)[i] = hv;
    reinterpret_cast<ushort4*>(l)[i] = lv;
}

// ---------------------------------------------------------------------------
// Pre-pass: W [rows(k)][cols(n)] fp32 -> WT hi/lo bf16 [n][k]
// ---------------------------------------------------------------------------
__global__ __launch_bounds__(256) void transpose_hilo(const float* __restrict__ src,
                                                      unsigned short* __restrict__ th,
                                                      unsigned short* __restrict__ tl,
                                                      int rows, int cols) {
    __shared__ float tile[32][33];
    const int c0 = blockIdx.x * 32, r0 = blockIdx.y * 32;
    const int tx = threadIdx.x & 31, ty = threadIdx.x >> 5;
    #pragma unroll
    for (int i = ty; i < 32; i += 8)
        tile[i][tx] = src[(long)(r0 + i) * cols + c0 + tx];
    __syncthreads();
    #pragma unroll
    for (int i = ty; i < 32; i += 8) {
        float v = tile[tx][i];
        unsigned short hv = f2bf(v);
        th[(long)(c0 + i) * rows + r0 + tx] = hv;
        tl[(long)(c0 + i) * rows + r0 + tx] = f2bf(v - bf2f(hv));
    }
}

// ---------------------------------------------------------------------------
// Pre-pass: pack binary mask into per-(16x64)-tile lane bitmasks.
// mbits[b][it(128)][jt(32)][lane(64)] : bit (nt*4+r) = mask[it*16 + (lane>>4)*4+r]
//                                                      [jt*64 + nt*16 + (lane&15)] != 0
// ---------------------------------------------------------------------------
__global__ __launch_bounds__(256) void pack_maskbits(const float* __restrict__ mask,
                                                     unsigned short* __restrict__ mbits) {
    const int it = blockIdx.x;      // 16-row tile index 0..127
    const int bb = blockIdx.y;
    const int t  = threadIdx.x;
    __shared__ unsigned char flags[16][256];
    const int R0 = it * 16;
    const int tl = t >> 6, ln = t & 63;
    const int lr = (ln >> 4) * 4, lc = ln & 15;

    for (int c0 = 0; c0 < SEQ; c0 += 256) {
        #pragma unroll
        for (int rr = 0; rr < 16; ++rr)
            flags[rr][t] = mask[((long)bb * SEQ + R0 + rr) * SEQ + c0 + t] != 0.f;
        __syncthreads();
        unsigned int bits = 0;
        #pragma unroll
        for (int nt = 0; nt < 4; ++nt)
            #pragma unroll
            for (int r = 0; r < 4; ++r)
                bits |= (unsigned int)flags[lr + r][tl * 64 + nt * 16 + lc] << (nt * 4 + r);
        mbits[(((long)bb * 128 + it) * 32 + (c0 >> 6) + tl) * 64 + ln] = (unsigned short)bits;
        __syncthreads();
    }
}

// ---------------------------------------------------------------------------
// bf16x3 MFMA GEMM (round-3 verified): C ~= AhBh + AhBl + AlBh, fp32 acc.
// ---------------------------------------------------------------------------
template <int EPI>
__global__ __launch_bounds__(256) void gemm_bf16x3(
    const unsigned short* __restrict__ Ahg, const unsigned short* __restrict__ Alg,
    const unsigned short* __restrict__ Bhg, const unsigned short* __restrict__ Blg,
    unsigned short* __restrict__ qb, unsigned short* __restrict__ kb,
    unsigned short* __restrict__ vtb,
    const float* __restrict__ bias, float* __restrict__ out) {
    __shared__ __align__(16) unsigned short Ah_s[128 * 32];
    __shared__ __align__(16) unsigned short Al_s[128 * 32];
    __shared__ __align__(16) unsigned short Bh_s[128 * 32];
    __shared__ __align__(16) unsigned short Bl_s[128 * 32];

    const int n0   = blockIdx.x * 128;
    const int m0   = blockIdx.y * 128;
    const int wave = threadIdx.x >> 6;
    const int lane = threadIdx.x & 63;
    const int l16  = lane & 15;
    const int g    = lane >> 4;
    const int wm   = wave & 1;
    const int wn   = wave >> 1;

    const int srow   = lane >> 2;
    const int schunk = (lane & 3) * 8;

    f32x4 acc[4][4] = {};

    for (int k0 = 0; k0 < DIM; k0 += 32) {
        #pragma unroll
        for (int i = 0; i < 2; ++i) {
            const int row = wave * 32 + i * 16;
            const long ga = (long)(m0 + row + srow) * DIM + k0 + schunk;
            const long gb = (long)(n0 + row + srow) * DIM + k0 + schunk;
            glds16(Ahg + ga, &Ah_s[row * 32]);
            glds16(Alg + ga, &Al_s[row * 32]);
            glds16(Bhg + gb, &Bh_s[row * 32]);
            glds16(Blg + gb, &Bl_s[row * 32]);
        }
        __syncthreads();

        short8 ah[4], al[4];
        #pragma unroll
        for (int mt = 0; mt < 4; ++mt) {
            const int r = (wm * 64 + mt * 16 + l16) * 32 + g * 8;
            ah[mt] = *reinterpret_cast<const short8*>(&Ah_s[r]);
            al[mt] = *reinterpret_cast<const short8*>(&Al_s[r]);
        }
        #pragma unroll
        for (int nt = 0; nt < 4; ++nt) {
            const int r = (wn * 64 + nt * 16 + l16) * 32 + g * 8;
            const short8 bh = *reinterpret_cast<const short8*>(&Bh_s[r]);
            const short8 bl = *reinterpret_cast<const short8*>(&Bl_s[r]);
            #pragma unroll
            for (int mt = 0; mt < 4; ++mt) {
                acc[mt][nt] = __builtin_amdgcn_mfma_f32_16x16x32_bf16(ah[mt], bh, acc[mt][nt], 0, 0, 0);
                acc[mt][nt] = __builtin_amdgcn_mfma_f32_16x16x32_bf16(ah[mt], bl, acc[mt][nt], 0, 0, 0);
                acc[mt][nt] = __builtin_amdgcn_mfma_f32_16x16x32_bf16(al[mt], bh, acc[mt][nt], 0, 0, 0);
            }
        }
        __syncthreads();
    }

    if constexpr (EPI == 0) {
        #pragma unroll
        for (int nt = 0; nt < 4; ++nt) {
            const int n     = n0 + wn * 64 + nt * 16 + l16;
            const int which = n >> 10;
            const int rem   = n & 1023;
            const int head  = rem >> 6;
            const int d     = rem & 63;
            #pragma unroll
            for (int mt = 0; mt < 4; ++mt) {
                #pragma unroll
                for (int r = 0; r < 4; ++r) {
                    const int m  = m0 + wm * 64 + mt * 16 + g * 4 + r;
                    const int bb = m >> 11;
                    const int li = m & 2047;
                    const int bh_i = bb * HEADS + head;
                    const float val = acc[mt][nt][r];
                    if (which == 0)
                        qb[((long)bh_i * SEQ + li) * DH + d] = f2bf(val * SCALE);
                    else if (which == 1)
                        kb[((long)bh_i * SEQ + li) * DH + d] = f2bf(val);
                    else
                        vtb[((long)bh_i * DH + d) * SEQ + li] = f2bf(val);
                }
            }
        }
    } else {
        #pragma unroll
        for (int nt = 0; nt < 4; ++nt) {
            const int n  = n0 + wn * 64 + nt * 16 + l16;
            const float bv = bias[n];
            #pragma unroll
            for (int mt = 0; mt < 4; ++mt) {
                #pragma unroll
                for (int r = 0; r < 4; ++r) {
                    const int m = m0 + wm * 64 + mt * 16 + g * 4 + r;
                    out[(long)m * DIM + n] = acc[mt][nt][r] + bv;
                }
            }
        }
    }
}

// ---------------------------------------------------------------------------
// MFMA flash attention v3: block = 64 q rows (4 waves x 16), full j-loop.
// K/V tiles staged in LDS via glds16 (shared by all waves), XOR-swizzled
// chunk layout (global chunk c of row r -> slot c^(r&7)) for conflict-free
// ds_read_b128 fragments. Mask = 1 bit/element via mbits. 2 barriers/iter.
// ---------------------------------------------------------------------------
__global__ __launch_bounds__(256) void attn_mfma(const unsigned short* __restrict__ qb,
                                                 const unsigned short* __restrict__ kb,
                                                 const unsigned short* __restrict__ vtb,
                                                 const unsigned short* __restrict__ mbits,
                                                 unsigned short* __restrict__ zh,
                                                 unsigned short* __restrict__ zl) {
    const int qt   = blockIdx.x;            // 0..31 (64-row q tiles)
    const int h    = blockIdx.y;
    const int bb   = blockIdx.z;
    const int bh   = bb * HEADS + h;
    const int wave = threadIdx.x >> 6;
    const int lane = threadIdx.x & 63;
    const int l16  = lane & 15;
    const int g    = lane >> 4;

    const int i0     = qt * 64;
    const int myrow0 = i0 + wave * 16;      // this wave's 16 q rows

    __shared__ __align__(16) unsigned short Ks[64 * 64];   // [j(64)][d-chunk swizzled]
    __shared__ __align__(16) unsigned short Vs[64 * 64];   // [d(64)][j-chunk swizzled]
    __shared__ __align__(16) unsigned short Ps[4][16][72]; // P staging, wave-private

    // staging lane decomposition: 8 rows x 8 chunks per glds16
    const int sr8 = lane >> 3;              // row within 8-row chunk
    const int scg = (lane & 7) ^ sr8;       // swizzled global chunk index
    const int sw  = l16 & 7;                // read-side swizzle key (= row&7)

    // Q fragments
    const unsigned short* qptr = qb + ((long)bh * SEQ + myrow0 + l16) * DH + g * 8;
    const short8 q0 = *reinterpret_cast<const short8*>(qptr);
    const short8 q1 = *reinterpret_cast<const short8*>(qptr + 32);

    f32x4 o[4] = {};
    float Zpm[4] = {0.f, 0.f, 0.f, 0.f};
    float m_w = -INFINITY;

    const unsigned short* mb =
        mbits + (((long)bb * 128 + (i0 >> 4) + wave) * 32) * 64 + lane;

    for (int jt = 0; jt < 32; ++jt) {
        const int j0 = jt * 64;

        // ---- stage K (j-rows) and V^T (d-rows) tiles: 4 glds16 per wave ----
        #pragma unroll
        for (int i = 0; i < 2; ++i) {
            const int row = wave * 16 + i * 8;                        // uniform
            glds16(kb  + ((long)bh * SEQ + j0 + row + sr8) * DH + scg * 8, &Ks[row * 64]);
            glds16(vtb + ((long)bh * DH  + row + sr8) * SEQ + j0 + scg * 8, &Vs[row * 64]);
        }
        __syncthreads();

        // ---- S = Q K^T ----
        f32x4 s[4];
        #pragma unroll
        for (int nt = 0; nt < 4; ++nt) {
            const int rbase = (nt * 16 + l16) * 64;
            const short8 k0 = *reinterpret_cast<const short8*>(&Ks[rbase + ((0 + g) ^ sw) * 8]);
            const short8 k1 = *reinterpret_cast<const short8*>(&Ks[rbase + ((4 + g) ^ sw) * 8]);
            f32x4 acc = {0.f, 0.f, 0.f, 0.f};
            acc = __builtin_amdgcn_mfma_f32_16x16x32_bf16(q0, k0, acc, 0, 0, 0);
            acc = __builtin_amdgcn_mfma_f32_16x16x32_bf16(q1, k1, acc, 0, 0, 0);
            s[nt] = acc;
        }

        // ---- wave-uniform tile max ----
        float tmax = fmaxf(fmaxf(fmaxf(s[0][0], s[0][1]), fmaxf(s[0][2], s[0][3])),
                           fmaxf(fmaxf(s[1][0], s[1][1]), fmaxf(s[1][2], s[1][3])));
        tmax = fmaxf(tmax, fmaxf(fmaxf(fmaxf(s[2][0], s[2][1]), fmaxf(s[2][2], s[2][3])),
                                 fmaxf(fmaxf(s[3][0], s[3][1]), fmaxf(s[3][2], s[3][3]))));
        #pragma unroll
        for (int off = 1; off < 64; off <<= 1)
            tmax = fmaxf(tmax, __shfl_xor(tmax, off, 64));
        const float tmax_u = __builtin_bit_cast(float,
            __builtin_amdgcn_readfirstlane(__builtin_bit_cast(int, tmax)));

        // ---- lazy rescale (wave-uniform branch) ----
        if (tmax_u > m_w) {
            const float alpha = __expf(m_w - tmax_u);   // jt 0: exp(-inf)=0
            m_w = tmax_u;
            #pragma unroll
            for (int r = 0; r < 4; ++r) Zpm[r] *= alpha;
            #pragma unroll
            for (int nt = 0; nt < 4; ++nt)
                #pragma unroll
                for (int r = 0; r < 4; ++r) o[nt][r] *= alpha;
        }

        // ---- p = exp(s - m) bit-masked, stage bf16 P ----
        const unsigned int bits = mb[jt * 64];
        #pragma unroll
        for (int nt = 0; nt < 4; ++nt) {
            #pragma unroll
            for (int r = 0; r < 4; ++r) {
                const float p  = __expf(s[nt][r] - m_w);
                const float pm = ((bits >> (nt * 4 + r)) & 1u) ? p : 0.f;
                Zpm[r] += pm;
                Ps[wave][g * 4 + r][nt * 16 + l16] = f2bf(pm);
            }
        }

        // ---- O += P V ----
        #pragma unroll
        for (int jc = 0; jc < 2; ++jc) {
            const short8 pf = *reinterpret_cast<const short8*>(&Ps[wave][l16][jc * 32 + g * 8]);
            #pragma unroll
            for (int nt = 0; nt < 4; ++nt) {
                const short8 vf = *reinterpret_cast<const short8*>(
                    &Vs[(nt * 16 + l16) * 64 + ((jc * 4 + g) ^ sw) * 8]);
                o[nt] = __builtin_amdgcn_mfma_f32_16x16x32_bf16(pf, vf, o[nt], 0, 0, 0);
            }
        }
        __syncthreads();
    }

    // ---- finalize (per wave, no combine needed) ----
    #pragma unroll
    for (int off = 1; off < 16; off <<= 1)
        #pragma unroll
        for (int r = 0; r < 4; ++r)
            Zpm[r] += __shfl_xor(Zpm[r], off, 64);
    float inv[4];
    #pragma unroll
    for (int r = 0; r < 4; ++r) inv[r] = 1.f / (Zpm[r] + 2048.0f * EPS);

    #pragma unroll
    for (int nt = 0; nt < 4; ++nt)
        #pragma unroll
        for (int r = 0; r < 4; ++r) {
            const int row = myrow0 + g * 4 + r;
            const long idx = ((long)bb * SEQ + row) * DIM + h * DH + nt * 16 + l16;
            const float val = o[nt][r] * inv[r];
            const unsigned short hv = f2bf(val);
            zh[idx] = hv;
            zl[idx] = f2bf(val - bf2f(hv));
        }
}

// ---------------------------------------------------------------------------
extern "C" void kernel_launch(void* const* d_in, const int* in_sizes, int n_in,
                              void* d_out, int out_size, void* d_ws, size_t ws_size,
                              hipStream_t stream) {
    const float* x     = (const float*)d_in[0];
    const float* mask  = (const float*)d_in[1];
    const float* W_qkv = (const float*)d_in[2];
    const float* W_out = (const float*)d_in[3];
    const float* b_out = (const float*)d_in[4];
    float* out = (float*)d_out;

    unsigned short* ws = (unsigned short*)d_ws;
    unsigned short* xh    = ws;                  // 4M  (reused as zh after gemm1)
    unsigned short* xl    = xh    + 4194304;     // 4M  (reused as zl)
    unsigned short* WqTh  = xl    + 4194304;     // 3M
    unsigned short* WqTl  = WqTh  + 3145728;     // 3M
    unsigned short* WoTh  = WqTl  + 3145728;     // 1M
    unsigned short* WoTl  = WoTh  + 1048576;     // 1M
    unsigned short* qb    = WoTl  + 1048576;     // 4M
    unsigned short* kb    = qb    + 4194304;     // 4M
    unsigned short* vtb   = kb    + 4194304;     // 4M
    unsigned short* mbits = vtb   + 4194304;     // 0.5M -> 57 MB total
    unsigned short* zzh   = xh;
    unsigned short* zzl   = xl;

    convert_hilo<<<4096, 256, 0, stream>>>(x, xh, xl);
    transpose_hilo<<<dim3(96, 32), 256, 0, stream>>>(W_qkv, WqTh, WqTl, 1024, 3072);
    transpose_hilo<<<dim3(32, 32), 256, 0, stream>>>(W_out, WoTh, WoTl, 1024, 1024);
    pack_maskbits<<<dim3(128, 2), 256, 0, stream>>>(mask, mbits);

    gemm_bf16x3<0><<<dim3(24, 32), 256, 0, stream>>>(xh, xl, WqTh, WqTl,
                                                     qb, kb, vtb, nullptr, nullptr);

    attn_mfma<<<dim3(SEQ / 64, HEADS, BATCH), 256, 0, stream>>>(qb, kb, vtb, mbits, zzh, zzl);

    gemm_bf16x3<1><<<dim3(8, 32), 256, 0, stream>>>(zzh, zzl, WoTh, WoTl,
                                                    nullptr, nullptr, nullptr, b_out, out);
}

// Round 6
// 299.041 us; speedup vs baseline: 1.6823x; 1.1960x over previous
//
#include <hip/hip_runtime.h>
#include <hip/hip_bf16.h>

// x: [2, 2048, 1024] f32; mask: [2, 2048, 2048] f32; W_qkv: [1024, 3072] f32
// W_out: [1024, 1024] f32; b_out: [1024] f32; out: [2, 2048, 1024] f32
#define BATCH 2
#define SEQ   2048
#define DIM   1024
#define HEADS 16
#define DH    64
#define N_QKV 3072
#define M_TOT 4096
#define SCALE 0.125f
#define EPS   1e-10f

typedef __attribute__((ext_vector_type(8))) short short8;
typedef __attribute__((ext_vector_type(4))) float f32x4;

static __device__ __forceinline__ unsigned short f2bf(float f) {
    __hip_bfloat16 h = __float2bfloat16(f);
    return *reinterpret_cast<unsigned short*>(&h);
}
static __device__ __forceinline__ float bf2f(unsigned short u) {
    unsigned int x = ((unsigned int)u) << 16;
    return __builtin_bit_cast(float, x);
}
static __device__ __forceinline__ void glds16(const void* g, void* l) {
    __builtin_amdgcn_global_load_lds((const __attribute__((address_space(1))) void*)g,
                                     (__attribute__((address_space(3))) void*)l,
                                     16, 0, 0);
}

// ---------------------------------------------------------------------------
// Pre-pass: fp32 -> bf16 (hi only; for GEMM1 inputs)
// ---------------------------------------------------------------------------
__global__ __launch_bounds__(256) void convert_hi(const float* __restrict__ s,
                                                  unsigned short* __restrict__ h) {
    const int i = blockIdx.x * 256 + threadIdx.x;
    float4 v = reinterpret_cast<const float4*>(s)[i];
    ushort4 hv;
    hv.x = f2bf(v.x); hv.y = f2bf(v.y); hv.z = f2bf(v.z); hv.w = f2bf(v.w);
    reinterpret_cast<ushort4*>(h)[i] = hv;
}

// ---------------------------------------------------------------------------
// Pre-pass: W [k][n] fp32 -> WT bf16 [n][k] (hi only)
// ---------------------------------------------------------------------------
__global__ __launch_bounds__(256) void transpose_hi(const float* __restrict__ src,
                                                    unsigned short* __restrict__ th,
                                                    int rows, int cols) {
    __shared__ float tile[32][33];
    const int c0 = blockIdx.x * 32, r0 = blockIdx.y * 32;
    const int tx = threadIdx.x & 31, ty = threadIdx.x >> 5;
    #pragma unroll
    for (int i = ty; i < 32; i += 8)
        tile[i][tx] = src[(long)(r0 + i) * cols + c0 + tx];
    __syncthreads();
    #pragma unroll
    for (int i = ty; i < 32; i += 8)
        th[(long)(c0 + i) * rows + r0 + tx] = f2bf(tile[tx][i]);
}

// ---------------------------------------------------------------------------
// Pre-pass: W [k][n] fp32 -> WT hi/lo bf16 [n][k] (for GEMM2's x3 path)
// ---------------------------------------------------------------------------
__global__ __launch_bounds__(256) void transpose_hilo(const float* __restrict__ src,
                                                      unsigned short* __restrict__ th,
                                                      unsigned short* __restrict__ tl,
                                                      int rows, int cols) {
    __shared__ float tile[32][33];
    const int c0 = blockIdx.x * 32, r0 = blockIdx.y * 32;
    const int tx = threadIdx.x & 31, ty = threadIdx.x >> 5;
    #pragma unroll
    for (int i = ty; i < 32; i += 8)
        tile[i][tx] = src[(long)(r0 + i) * cols + c0 + tx];
    __syncthreads();
    #pragma unroll
    for (int i = ty; i < 32; i += 8) {
        float v = tile[tx][i];
        unsigned short hv = f2bf(v);
        th[(long)(c0 + i) * rows + r0 + tx] = hv;
        tl[(long)(c0 + i) * rows + r0 + tx] = f2bf(v - bf2f(hv));
    }
}

// ---------------------------------------------------------------------------
// Pre-pass: pack binary mask into per-(16x64)-tile lane bitmasks.
// ---------------------------------------------------------------------------
__global__ __launch_bounds__(256) void pack_maskbits(const float* __restrict__ mask,
                                                     unsigned short* __restrict__ mbits) {
    const int it = blockIdx.x;
    const int bb = blockIdx.y;
    const int t  = threadIdx.x;
    __shared__ unsigned char flags[16][256];
    const int R0 = it * 16;
    const int tl = t >> 6, ln = t & 63;
    const int lr = (ln >> 4) * 4, lc = ln & 15;

    for (int c0 = 0; c0 < SEQ; c0 += 256) {
        #pragma unroll
        for (int rr = 0; rr < 16; ++rr)
            flags[rr][t] = mask[((long)bb * SEQ + R0 + rr) * SEQ + c0 + t] != 0.f;
        __syncthreads();
        unsigned int bits = 0;
        #pragma unroll
        for (int nt = 0; nt < 4; ++nt)
            #pragma unroll
            for (int r = 0; r < 4; ++r)
                bits |= (unsigned int)flags[lr + r][tl * 64 + nt * 16 + lc] << (nt * 4 + r);
        mbits[(((long)bb * 128 + it) * 32 + (c0 >> 6) + tl) * 64 + ln] = (unsigned short)bits;
        __syncthreads();
    }
}

// ---------------------------------------------------------------------------
// GEMM 1 (NEW): plain bf16 MFMA, BK=64, XOR-swizzled LDS (conflict-free).
// qkv = x @ W_qkv with scatter epilogue to q (scaled) / k / v^T bf16 buffers.
// 128x128 tile, 4 waves -> 64x64 each; per K-step/wave: 32 MFMA, 16 ds_read,
// 8 glds16. Accuracy: inputs bf16 (outputs are rounded to bf16 anyway).
// ---------------------------------------------------------------------------
__global__ __launch_bounds__(256) void gemm_qkv_bf16(
    const unsigned short* __restrict__ Ahg, const unsigned short* __restrict__ Bhg,
    unsigned short* __restrict__ qb, unsigned short* __restrict__ kb,
    unsigned short* __restrict__ vtb) {
    __shared__ __align__(16) unsigned short As[128 * 64];
    __shared__ __align__(16) unsigned short Bs[128 * 64];

    const int n0   = blockIdx.x * 128;
    const int m0   = blockIdx.y * 128;
    const int wave = threadIdx.x >> 6;
    const int lane = threadIdx.x & 63;
    const int l16  = lane & 15;
    const int g    = lane >> 4;
    const int wm   = wave & 1;
    const int wn   = wave >> 1;
    const int sw   = l16 & 7;              // read-side swizzle key

    const int sr8 = lane >> 3;             // staging: row within 8-row chunk
    const int scg = (lane & 7) ^ sr8;      // staging: swizzled global chunk

    f32x4 acc[4][4] = {};

    for (int k0 = 0; k0 < DIM; k0 += 64) {
        #pragma unroll
        for (int i = 0; i < 4; ++i) {
            const int row = wave * 32 + i * 8;                        // uniform
            glds16(Ahg + (long)(m0 + row + sr8) * DIM + k0 + scg * 8, &As[row * 64]);
            glds16(Bhg + (long)(n0 + row + sr8) * DIM + k0 + scg * 8, &Bs[row * 64]);
        }
        __syncthreads();

        short8 a[4][2];
        #pragma unroll
        for (int mt = 0; mt < 4; ++mt) {
            const int rbase = (wm * 64 + mt * 16 + l16) * 64;
            #pragma unroll
            for (int kc = 0; kc < 2; ++kc)
                a[mt][kc] = *reinterpret_cast<const short8*>(
                    &As[rbase + (((kc * 4 + g) ^ sw) * 8)]);
        }
        #pragma unroll
        for (int nt = 0; nt < 4; ++nt) {
            const int rbase = (wn * 64 + nt * 16 + l16) * 64;
            const short8 b0 = *reinterpret_cast<const short8*>(&Bs[rbase + (((0 + g) ^ sw) * 8)]);
            const short8 b1 = *reinterpret_cast<const short8*>(&Bs[rbase + (((4 + g) ^ sw) * 8)]);
            #pragma unroll
            for (int mt = 0; mt < 4; ++mt) {
                acc[mt][nt] = __builtin_amdgcn_mfma_f32_16x16x32_bf16(a[mt][0], b0, acc[mt][nt], 0, 0, 0);
                acc[mt][nt] = __builtin_amdgcn_mfma_f32_16x16x32_bf16(a[mt][1], b1, acc[mt][nt], 0, 0, 0);
            }
        }
        __syncthreads();
    }

    #pragma unroll
    for (int nt = 0; nt < 4; ++nt) {
        const int n     = n0 + wn * 64 + nt * 16 + l16;
        const int which = n >> 10;
        const int rem   = n & 1023;
        const int head  = rem >> 6;
        const int d     = rem & 63;
        #pragma unroll
        for (int mt = 0; mt < 4; ++mt) {
            #pragma unroll
            for (int r = 0; r < 4; ++r) {
                const int m  = m0 + wm * 64 + mt * 16 + g * 4 + r;
                const int bb = m >> 11;
                const int li = m & 2047;
                const int bh_i = bb * HEADS + head;
                const float val = acc[mt][nt][r];
                if (which == 0)
                    qb[((long)bh_i * SEQ + li) * DH + d] = f2bf(val * SCALE);
                else if (which == 1)
                    kb[((long)bh_i * SEQ + li) * DH + d] = f2bf(val);
                else
                    vtb[((long)bh_i * DH + d) * SEQ + li] = f2bf(val);
            }
        }
    }
}

// ---------------------------------------------------------------------------
// GEMM 2: bf16x3 MFMA (round-3 verified): out = z @ W_out + bias, fp32 out.
// ---------------------------------------------------------------------------
__global__ __launch_bounds__(256) void gemm_out_bf16x3(
    const unsigned short* __restrict__ Ahg, const unsigned short* __restrict__ Alg,
    const unsigned short* __restrict__ Bhg, const unsigned short* __restrict__ Blg,
    const float* __restrict__ bias, float* __restrict__ out) {
    __shared__ __align__(16) unsigned short Ah_s[128 * 32];
    __shared__ __align__(16) unsigned short Al_s[128 * 32];
    __shared__ __align__(16) unsigned short Bh_s[128 * 32];
    __shared__ __align__(16) unsigned short Bl_s[128 * 32];

    const int n0   = blockIdx.x * 128;
    const int m0   = blockIdx.y * 128;
    const int wave = threadIdx.x >> 6;
    const int lane = threadIdx.x & 63;
    const int l16  = lane & 15;
    const int g    = lane >> 4;
    const int wm   = wave & 1;
    const int wn   = wave >> 1;

    const int srow   = lane >> 2;
    const int schunk = (lane & 3) * 8;

    f32x4 acc[4][4] = {};

    for (int k0 = 0; k0 < DIM; k0 += 32) {
        #pragma unroll
        for (int i = 0; i < 2; ++i) {
            const int row = wave * 32 + i * 16;
            const long ga = (long)(m0 + row + srow) * DIM + k0 + schunk;
            const long gb = (long)(n0 + row + srow) * DIM + k0 + schunk;
            glds16(Ahg + ga, &Ah_s[row * 32]);
            glds16(Alg + ga, &Al_s[row * 32]);
            glds16(Bhg + gb, &Bh_s[row * 32]);
            glds16(Blg + gb, &Bl_s[row * 32]);
        }
        __syncthreads();

        short8 ah[4], al[4];
        #pragma unroll
        for (int mt = 0; mt < 4; ++mt) {
            const int r = (wm * 64 + mt * 16 + l16) * 32 + g * 8;
            ah[mt] = *reinterpret_cast<const short8*>(&Ah_s[r]);
            al[mt] = *reinterpret_cast<const short8*>(&Al_s[r]);
        }
        #pragma unroll
        for (int nt = 0; nt < 4; ++nt) {
            const int r = (wn * 64 + nt * 16 + l16) * 32 + g * 8;
            const short8 bh = *reinterpret_cast<const short8*>(&Bh_s[r]);
            const short8 bl = *reinterpret_cast<const short8*>(&Bl_s[r]);
            #pragma unroll
            for (int mt = 0; mt < 4; ++mt) {
                acc[mt][nt] = __builtin_amdgcn_mfma_f32_16x16x32_bf16(ah[mt], bh, acc[mt][nt], 0, 0, 0);
                acc[mt][nt] = __builtin_amdgcn_mfma_f32_16x16x32_bf16(ah[mt], bl, acc[mt][nt], 0, 0, 0);
                acc[mt][nt] = __builtin_amdgcn_mfma_f32_16x16x32_bf16(al[mt], bh, acc[mt][nt], 0, 0, 0);
            }
        }
        __syncthreads();
    }

    #pragma unroll
    for (int nt = 0; nt < 4; ++nt) {
        const int n  = n0 + wn * 64 + nt * 16 + l16;
        const float bv = bias[n];
        #pragma unroll
        for (int mt = 0; mt < 4; ++mt) {
            #pragma unroll
            for (int r = 0; r < 4; ++r) {
                const int m = m0 + wm * 64 + mt * 16 + g * 4 + r;
                out[(long)m * DIM + n] = acc[mt][nt][r] + bv;
            }
        }
    }
}

// ---------------------------------------------------------------------------
// MFMA flash attention v3 (round-5 verified): block = 64 q rows, K/V staged
// in LDS via glds16 (XOR-swizzled), 1-bit mask, 2 barriers/iter.
// ---------------------------------------------------------------------------
__global__ __launch_bounds__(256) void attn_mfma(const unsigned short* __restrict__ qb,
                                                 const unsigned short* __restrict__ kb,
                                                 const unsigned short* __restrict__ vtb,
                                                 const unsigned short* __restrict__ mbits,
                                                 unsigned short* __restrict__ zh,
                                                 unsigned short* __restrict__ zl) {
    const int qt   = blockIdx.x;
    const int h    = blockIdx.y;
    const int bb   = blockIdx.z;
    const int bh   = bb * HEADS + h;
    const int wave = threadIdx.x >> 6;
    const int lane = threadIdx.x & 63;
    const int l16  = lane & 15;
    const int g    = lane >> 4;

    const int i0     = qt * 64;
    const int myrow0 = i0 + wave * 16;

    __shared__ __align__(16) unsigned short Ks[64 * 64];
    __shared__ __align__(16) unsigned short Vs[64 * 64];
    __shared__ __align__(16) unsigned short Ps[4][16][72];

    const int sr8 = lane >> 3;
    const int scg = (lane & 7) ^ sr8;
    const int sw  = l16 & 7;

    const unsigned short* qptr = qb + ((long)bh * SEQ + myrow0 + l16) * DH + g * 8;
    const short8 q0 = *reinterpret_cast<const short8*>(qptr);
    const short8 q1 = *reinterpret_cast<const short8*>(qptr + 32);

    f32x4 o[4] = {};
    float Zpm[4] = {0.f, 0.f, 0.f, 0.f};
    float m_w = -INFINITY;

    const unsigned short* mb =
        mbits + (((long)bb * 128 + (i0 >> 4) + wave) * 32) * 64 + lane;

    for (int jt = 0; jt < 32; ++jt) {
        const int j0 = jt * 64;

        #pragma unroll
        for (int i = 0; i < 2; ++i) {
            const int row = wave * 16 + i * 8;
            glds16(kb  + ((long)bh * SEQ + j0 + row + sr8) * DH + scg * 8, &Ks[row * 64]);
            glds16(vtb + ((long)bh * DH  + row + sr8) * SEQ + j0 + scg * 8, &Vs[row * 64]);
        }
        __syncthreads();

        f32x4 s[4];
        #pragma unroll
        for (int nt = 0; nt < 4; ++nt) {
            const int rbase = (nt * 16 + l16) * 64;
            const short8 k0 = *reinterpret_cast<const short8*>(&Ks[rbase + ((0 + g) ^ sw) * 8]);
            const short8 k1 = *reinterpret_cast<const short8*>(&Ks[rbase + ((4 + g) ^ sw) * 8]);
            f32x4 acc = {0.f, 0.f, 0.f, 0.f};
            acc = __builtin_amdgcn_mfma_f32_16x16x32_bf16(q0, k0, acc, 0, 0, 0);
            acc = __builtin_amdgcn_mfma_f32_16x16x32_bf16(q1, k1, acc, 0, 0, 0);
            s[nt] = acc;
        }

        float tmax = fmaxf(fmaxf(fmaxf(s[0][0], s[0][1]), fmaxf(s[0][2], s[0][3])),
                           fmaxf(fmaxf(s[1][0], s[1][1]), fmaxf(s[1][2], s[1][3])));
        tmax = fmaxf(tmax, fmaxf(fmaxf(fmaxf(s[2][0], s[2][1]), fmaxf(s[2][2], s[2][3])),
                                 fmaxf(fmaxf(s[3][0], s[3][1]), fmaxf(s[3][2], s[3][3]))));
        #pragma unroll
        for (int off = 1; off < 64; off <<= 1)
            tmax = fmaxf(tmax, __shfl_xor(tmax, off, 64));
        const float tmax_u = __builtin_bit_cast(float,
            __builtin_amdgcn_readfirstlane(__builtin_bit_cast(int, tmax)));

        if (tmax_u > m_w) {
            const float alpha = __expf(m_w - tmax_u);
            m_w = tmax_u;
            #pragma unroll
            for (int r = 0; r < 4; ++r) Zpm[r] *= alpha;
            #pragma unroll
            for (int nt = 0; nt < 4; ++nt)
                #pragma unroll
                for (int r = 0; r < 4; ++r) o[nt][r] *= alpha;
        }

        const unsigned int bits = mb[jt * 64];
        #pragma unroll
        for (int nt = 0; nt < 4; ++nt) {
            #pragma unroll
            for (int r = 0; r < 4; ++r) {
                const float p  = __expf(s[nt][r] - m_w);
                const float pm = ((bits >> (nt * 4 + r)) & 1u) ? p : 0.f;
                Zpm[r] += pm;
                Ps[wave][g * 4 + r][nt * 16 + l16] = f2bf(pm);
            }
        }

        #pragma unroll
        for (int jc = 0; jc < 2; ++jc) {
            const short8 pf = *reinterpret_cast<const short8*>(&Ps[wave][l16][jc * 32 + g * 8]);
            #pragma unroll
            for (int nt = 0; nt < 4; ++nt) {
                const short8 vf = *reinterpret_cast<const short8*>(
                    &Vs[(nt * 16 + l16) * 64 + ((jc * 4 + g) ^ sw) * 8]);
                o[nt] = __builtin_amdgcn_mfma_f32_16x16x32_bf16(pf, vf, o[nt], 0, 0, 0);
            }
        }
        __syncthreads();
    }

    #pragma unroll
    for (int off = 1; off < 16; off <<= 1)
        #pragma unroll
        for (int r = 0; r < 4; ++r)
            Zpm[r] += __shfl_xor(Zpm[r], off, 64);
    float inv[4];
    #pragma unroll
    for (int r = 0; r < 4; ++r) inv[r] = 1.f / (Zpm[r] + 2048.0f * EPS);

    #pragma unroll
    for (int nt = 0; nt < 4; ++nt)
        #pragma unroll
        for (int r = 0; r < 4; ++r) {
            const int row = myrow0 + g * 4 + r;
            const long idx = ((long)bb * SEQ + row) * DIM + h * DH + nt * 16 + l16;
            const float val = o[nt][r] * inv[r];
            const unsigned short hv = f2bf(val);
            zh[idx] = hv;
            zl[idx] = f2bf(val - bf2f(hv));
        }
}

// ---------------------------------------------------------------------------
extern "C" void kernel_launch(void* const* d_in, const int* in_sizes, int n_in,
                              void* d_out, int out_size, void* d_ws, size_t ws_size,
                              hipStream_t stream) {
    const float* x     = (const float*)d_in[0];
    const float* mask  = (const float*)d_in[1];
    const float* W_qkv = (const float*)d_in[2];
    const float* W_out = (const float*)d_in[3];
    const float* b_out = (const float*)d_in[4];
    float* out = (float*)d_out;

    unsigned short* ws = (unsigned short*)d_ws;
    unsigned short* xh    = ws;                  // 4M  (reused as zh after gemm1)
    unsigned short* xl    = xh    + 4194304;     // 4M  (zl; unused pre-attention)
    unsigned short* WqTh  = xl    + 4194304;     // 3M
    unsigned short* WqTl  = WqTh  + 3145728;     // 3M (unused now, kept for layout)
    unsigned short* WoTh  = WqTl  + 3145728;     // 1M
    unsigned short* WoTl  = WoTh  + 1048576;     // 1M
    unsigned short* qb    = WoTl  + 1048576;     // 4M
    unsigned short* kb    = qb    + 4194304;     // 4M
    unsigned short* vtb   = kb    + 4194304;     // 4M
    unsigned short* mbits = vtb   + 4194304;     // 0.5M -> 57 MB total
    unsigned short* zzh   = xh;
    unsigned short* zzl   = xl;

    convert_hi<<<4096, 256, 0, stream>>>(x, xh);
    transpose_hi<<<dim3(96, 32), 256, 0, stream>>>(W_qkv, WqTh, 1024, 3072);
    transpose_hilo<<<dim3(32, 32), 256, 0, stream>>>(W_out, WoTh, WoTl, 1024, 1024);
    pack_maskbits<<<dim3(128, 2), 256, 0, stream>>>(mask, mbits);

    gemm_qkv_bf16<<<dim3(24, 32), 256, 0, stream>>>(xh, WqTh, qb, kb, vtb);

    attn_mfma<<<dim3(SEQ / 64, HEADS, BATCH), 256, 0, stream>>>(qb, kb, vtb, mbits, zzh, zzl);

    gemm_out_bf16x3<<<dim3(8, 32), 256, 0, stream>>>(zzh, zzl, WoTh, WoTl, b_out, out);
}